// Round 7
// baseline (385.310 us; speedup 1.0000x reference)
//
#include <hip/hip_runtime.h>
#include <hip/hip_bf16.h>
#include <stdint.h>

// Problem: B=8, T=4096, C=1024, D=128 single-head causal attention, fp32 in/out.
// Pipeline: prep_w (W->bf16, transposed) ; qkv_gemm (fused: x@{Wq,Wk,Wv} one pass) ;
// attn_fwd (flash attention, bf16 MFMA, fp32 out).
// R6: uniform-work chunk pairs (g, 255-g) + split-KV x4 with 4-wave merge;
//     fused QKV projection (x read once instead of 3x).

typedef __attribute__((ext_vector_type(8))) short short8;   // 8 bf16 (4 VGPRs)
typedef __attribute__((ext_vector_type(4))) float f32x4;
typedef __attribute__((ext_vector_type(4))) unsigned short u16x4;

#define NB 8
#define NT 4096
#define NC 1024
#define ND 128

__device__ __forceinline__ unsigned short f2bf(float f) {
    union { float f; uint32_t u; } v; v.f = f;
    uint32_t u = v.u;
    return (unsigned short)((u + 0x7FFFu + ((u >> 16) & 1u)) >> 16);  // RNE
}

// ---------------- W -> bf16, transposed: Wbt[w][n][k] = W_w[k][n] ----------------
__global__ void prep_w(const float* __restrict__ Wq, const float* __restrict__ Wk,
                       const float* __restrict__ Wv, unsigned short* __restrict__ Wbt) {
    int idx = blockIdx.x * 256 + threadIdx.x;          // 0 .. 3*128*1024-1
    int w = idx >> 17;                                  // 131072 per matrix
    int rem = idx & 131071;
    int n = rem >> 10;
    int k = rem & 1023;
    const float* W = (w == 0) ? Wq : (w == 1) ? Wk : Wv;
    Wbt[idx] = f2bf(W[k * ND + n]);
}

// ---------------- fused QKV projection: x[32768][1024] @ {Wq,Wk,Wv} ----------------
// grid 512: blockIdx.x = 64-row M-tile. x staged once, used for all 3 matrices.
// waves: wr = w>>1 (32-row half), wc = w&1 (64-col half). acc[3][2][4] f32x4 = 96 VGPR.
__global__ __launch_bounds__(256, 2)
void qkv_gemm(const float* __restrict__ x, const unsigned short* __restrict__ Wbt,
              unsigned short* __restrict__ Qo, unsigned short* __restrict__ Ko,
              unsigned short* __restrict__ Vto) {
    __shared__ __align__(16) unsigned short xl[64][40];   // 32 + 8 pad (bf16)
    const int mt = blockIdx.x;
    const int tid = threadIdx.x;
    const int lane = tid & 63;
    const int w = tid >> 6;
    const int wr = w >> 1, wc = w & 1;
    const int l15 = lane & 15, lg = lane >> 4;
    const int m0 = mt * 64;

    f32x4 acc[3][2][4];
#pragma unroll
    for (int nt = 0; nt < 3; ++nt)
#pragma unroll
        for (int mi = 0; mi < 2; ++mi)
#pragma unroll
            for (int ni = 0; ni < 4; ++ni) acc[nt][mi][ni] = (f32x4)0.0f;

    for (int ks = 0; ks < 32; ++ks) {
        const int k0 = ks * 32;
        // stage x tile (64 x 32 fp32) -> bf16 LDS: 512 f32x4 chunks / 256 threads
#pragma unroll
        for (int i = 0; i < 2; ++i) {
            int f = tid + 256 * i;
            int row = f >> 3, c4 = (f & 7) * 4;
            f32x4 v = *reinterpret_cast<const f32x4*>(&x[(size_t)(m0 + row) * NC + k0 + c4]);
            u16x4 bv;
#pragma unroll
            for (int e = 0; e < 4; ++e) bv[e] = f2bf(v[e]);
            *reinterpret_cast<u16x4*>(&xl[row][c4]) = bv;
        }
        __syncthreads();
        short8 a[2];
#pragma unroll
        for (int mi = 0; mi < 2; ++mi)
            a[mi] = *reinterpret_cast<const short8*>(&xl[wr * 32 + mi * 16 + l15][lg * 8]);
#pragma unroll
        for (int nt = 0; nt < 3; ++nt) {
            const unsigned short* Wn = Wbt + (size_t)nt * (ND * NC);
#pragma unroll
            for (int ni = 0; ni < 4; ++ni) {
                short8 bb = *reinterpret_cast<const short8*>(
                    &Wn[(size_t)(wc * 64 + ni * 16 + l15) * NC + k0 + lg * 8]);
                acc[nt][0][ni] = __builtin_amdgcn_mfma_f32_16x16x32_bf16(
                    a[0], bb, acc[nt][0][ni], 0, 0, 0);
                acc[nt][1][ni] = __builtin_amdgcn_mfma_f32_16x16x32_bf16(
                    a[1], bb, acc[nt][1][ni], 0, 0, 0);
            }
        }
        __syncthreads();
    }
    // epilogue: C/D layout col=lane&15, row=(lane>>4)*4+reg
#pragma unroll
    for (int nt = 0; nt < 3; ++nt)
#pragma unroll
        for (int mi = 0; mi < 2; ++mi)
#pragma unroll
            for (int ni = 0; ni < 4; ++ni)
#pragma unroll
                for (int r = 0; r < 4; ++r) {
                    int row = m0 + wr * 32 + mi * 16 + lg * 4 + r;
                    int col = wc * 64 + ni * 16 + l15;
                    unsigned short bv = f2bf(acc[nt][mi][ni][r]);
                    if (nt == 0) Qo[(size_t)row * ND + col] = bv;
                    else if (nt == 1) Ko[(size_t)row * ND + col] = bv;
                    else {
                        int bb2 = row >> 12, t = row & 4095;
                        Vto[((size_t)(bb2 * ND + col)) * NT + t] = bv;
                    }
                }
}

// ---------------- flash attention, causal, uniform-work + split-KV x4 ----------------
// 1024 blocks x 256 threads; block -> (batch b = bid&7, pair pid = bid>>3).
// Block processes 16-row q-chunks g = pid then g = 255-pid (work sum is constant).
// All 4 waves work on the SAME chunk with 4-way KV split: wave w takes
// s0 = w*64, w*64+256, ... Partial (m,l,O) merged through LDS (wave 0 finalizes).
// b = bid&7 keeps each XCD on one batch's K/V (2 MB, fits 4 MB XCD L2).
__global__ __launch_bounds__(256, 4)
void attn_fwd(const unsigned short* __restrict__ Q, const unsigned short* __restrict__ K,
              const unsigned short* __restrict__ Vt, float* __restrict__ out) {
    __shared__ __align__(16) unsigned short plds[4][16][72];  // per-wave P buffer
    __shared__ __align__(16) float oB[3][16][132];            // waves 1..3 partial O
    __shared__ float mlW[4][2][16];                            // per-wave m,l

    const int bid = blockIdx.x;
    const int pid = bid >> 3, b = bid & 7;
    const int tid = threadIdx.x;
    const int w = tid >> 6, lane = tid & 63;
    const int l15 = lane & 15, lg = lane >> 4;
    const int wk = w;                 // KV split index 0..3

    const float sc = 0.08838834764831845f;     // 1/sqrt(128)
    const float L2E = 1.4426950408889634f;

    const unsigned short* Kbase = &K[(size_t)b * NT * ND];
    const unsigned short* Vbase = &Vt[(size_t)b * ND * NT];

    for (int half = 0; half < 2; ++half) {
        const int g = half ? (255 - pid) : pid;   // 16-row chunk index within batch
        const int qw0 = g * 16;
        const int s0max = (qw0 >> 6) << 6;        // last 64-wide KV tile start

        // Q fragments: A-frag lane l holds Q[m=l&15][k-chunk per l>>4]
        short8 qf[4];
        const size_t qbase = ((size_t)b * NT + qw0 + l15) * ND;
#pragma unroll
        for (int c = 0; c < 4; ++c)
            qf[c] = *reinterpret_cast<const short8*>(&Q[qbase + c * 32 + lg * 8]);

        f32x4 o[8];
#pragma unroll
        for (int jn = 0; jn < 8; ++jn) o[jn] = (f32x4)0.0f;
        float mrow[4], lsum[4];
#pragma unroll
        for (int r = 0; r < 4; ++r) { mrow[r] = -1e30f; lsum[r] = 0.0f; }

        for (int s0 = wk * 64; s0 <= s0max; s0 += 256) {
            // ---- S = Q K^T (16 x 64 per wave); reuse s[] as p[] ----
            f32x4 s[4];
#pragma unroll
            for (int j = 0; j < 4; ++j) s[j] = (f32x4)0.0f;
            const unsigned short* Kb = Kbase + ((size_t)(s0 + l15)) * ND;
            __builtin_amdgcn_s_setprio(1);
#pragma unroll
            for (int j = 0; j < 4; ++j)
#pragma unroll
                for (int c = 0; c < 4; ++c) {
                    short8 kf = *reinterpret_cast<const short8*>(
                        &Kb[(size_t)j * 16 * ND + c * 32 + lg * 8]);
                    s[j] = __builtin_amdgcn_mfma_f32_16x16x32_bf16(qf[c], kf, s[j], 0, 0, 0);
                }
            __builtin_amdgcn_s_setprio(0);

            // ---- prefetch V half (jn=0..3): latency hides under softmax ----
            short8 vf0[8];
#pragma unroll
            for (int jn = 0; jn < 4; ++jn)
#pragma unroll
                for (int kc = 0; kc < 2; ++kc)
                    vf0[jn * 2 + kc] = *reinterpret_cast<const short8*>(
                        &Vbase[((size_t)(jn * 16 + l15)) * NT + s0 + kc * 32 + lg * 8]);

            // ---- softmax (online) ----
            const bool diag = (s0 + 64 > qw0);
            float tmax[4];
#pragma unroll
            for (int r = 0; r < 4; ++r) tmax[r] = -1e30f;
#pragma unroll
            for (int j = 0; j < 4; ++j)
#pragma unroll
                for (int r = 0; r < 4; ++r) {
                    float sv = s[j][r] * sc;
                    if (diag) {
                        int qrow = qw0 + lg * 4 + r;
                        int scol = s0 + j * 16 + l15;
                        if (scol > qrow) sv = -1e30f;
                    }
                    s[j][r] = sv;
                    tmax[r] = fmaxf(tmax[r], sv);
                }
#pragma unroll
            for (int r = 0; r < 4; ++r) {
#pragma unroll
                for (int off = 1; off < 16; off <<= 1)
                    tmax[r] = fmaxf(tmax[r], __shfl_xor(tmax[r], off, 64));
            }
            float alpha[4], psum[4];
#pragma unroll
            for (int r = 0; r < 4; ++r) {
                float mn = fmaxf(mrow[r], tmax[r]);
                alpha[r] = exp2f((mrow[r] - mn) * L2E);
                mrow[r] = mn;
                psum[r] = 0.0f;
            }
#pragma unroll
            for (int j = 0; j < 4; ++j)
#pragma unroll
                for (int r = 0; r < 4; ++r) {
                    float pv = exp2f((s[j][r] - mrow[r]) * L2E);
                    s[j][r] = pv;
                    psum[r] += pv;
                }
#pragma unroll
            for (int r = 0; r < 4; ++r) {
#pragma unroll
                for (int off = 1; off < 16; off <<= 1)
                    psum[r] += __shfl_xor(psum[r], off, 64);
                lsum[r] = lsum[r] * alpha[r] + psum[r];
            }
            // rescale O
#pragma unroll
            for (int jn = 0; jn < 8; ++jn)
#pragma unroll
                for (int r = 0; r < 4; ++r) o[jn][r] *= alpha[r];

            // ---- P -> LDS (D-layout coords), reload as A-frags ----
#pragma unroll
            for (int j = 0; j < 4; ++j)
#pragma unroll
                for (int r = 0; r < 4; ++r)
                    plds[w][lg * 4 + r][j * 16 + l15] = f2bf(s[j][r]);
            asm volatile("s_waitcnt lgkmcnt(0)" ::: "memory");
            short8 pa[2];
#pragma unroll
            for (int kc = 0; kc < 2; ++kc)
                pa[kc] = *reinterpret_cast<const short8*>(&plds[w][l15][kc * 32 + lg * 8]);

            // ---- O += P V : half 0 from prefetched regs, half 1 inline ----
            __builtin_amdgcn_s_setprio(1);
#pragma unroll
            for (int jn = 0; jn < 4; ++jn)
#pragma unroll
                for (int kc = 0; kc < 2; ++kc)
                    o[jn] = __builtin_amdgcn_mfma_f32_16x16x32_bf16(
                        pa[kc], vf0[jn * 2 + kc], o[jn], 0, 0, 0);
#pragma unroll
            for (int jn = 4; jn < 8; ++jn)
#pragma unroll
                for (int kc = 0; kc < 2; ++kc) {
                    short8 vf = *reinterpret_cast<const short8*>(
                        &Vbase[((size_t)(jn * 16 + l15)) * NT + s0 + kc * 32 + lg * 8]);
                    o[jn] = __builtin_amdgcn_mfma_f32_16x16x32_bf16(pa[kc], vf, o[jn], 0, 0, 0);
                }
            __builtin_amdgcn_s_setprio(0);
        }

        // ---- 4-wave merge: waves 1..3 publish, wave 0 finalizes ----
        if (l15 == 0) {
#pragma unroll
            for (int r = 0; r < 4; ++r) {
                mlW[w][0][lg * 4 + r] = mrow[r];
                mlW[w][1][lg * 4 + r] = lsum[r];
            }
        }
        if (w > 0) {
#pragma unroll
            for (int jn = 0; jn < 8; ++jn)
#pragma unroll
                for (int r = 0; r < 4; ++r)
                    oB[w - 1][lg * 4 + r][jn * 16 + l15] = o[jn][r];
        }
        __syncthreads();
        if (w == 0) {
            float e0[4], e1[4], e2[4], e3[4], rL[4];
#pragma unroll
            for (int r = 0; r < 4; ++r) {
                int rr = lg * 4 + r;
                float m1 = mlW[1][0][rr], m2 = mlW[2][0][rr], m3 = mlW[3][0][rr];
                float M = fmaxf(fmaxf(mrow[r], m1), fmaxf(m2, m3));
                e0[r] = exp2f((mrow[r] - M) * L2E);
                e1[r] = exp2f((m1 - M) * L2E);
                e2[r] = exp2f((m2 - M) * L2E);
                e3[r] = exp2f((m3 - M) * L2E);
                float L = lsum[r] * e0[r] + mlW[1][1][rr] * e1[r]
                        + mlW[2][1][rr] * e2[r] + mlW[3][1][rr] * e3[r];
                rL[r] = 1.0f / L;
            }
#pragma unroll
            for (int jn = 0; jn < 8; ++jn)
#pragma unroll
                for (int r = 0; r < 4; ++r) {
                    int rr = lg * 4 + r, cc = jn * 16 + l15;
                    float v = o[jn][r] * e0[r]
                            + oB[0][rr][cc] * e1[r]
                            + oB[1][rr][cc] * e2[r]
                            + oB[2][rr][cc] * e3[r];
                    out[((size_t)b * NT + qw0 + rr) * ND + cc] = v * rL[r];
                }
        }
        __syncthreads();   // protect LDS reuse by the second chunk
    }
}

extern "C" void kernel_launch(void* const* d_in, const int* in_sizes, int n_in,
                              void* d_out, int out_size, void* d_ws, size_t ws_size,
                              hipStream_t stream) {
    const float* x  = (const float*)d_in[0];
    const float* Wq = (const float*)d_in[1];
    const float* Wk = (const float*)d_in[2];
    const float* Wv = (const float*)d_in[3];
    float* out = (float*)d_out;

    unsigned short* ws  = (unsigned short*)d_ws;
    unsigned short* Wbt = ws;                               // 3*128*1024
    unsigned short* Qb  = Wbt + 3 * ND * NC;                // 8*4096*128
    unsigned short* Kb  = Qb + (size_t)NB * NT * ND;
    unsigned short* Vtb = Kb + (size_t)NB * NT * ND;        // transposed [B][D][T]

    prep_w<<<1536, 256, 0, stream>>>(Wq, Wk, Wv, Wbt);
    qkv_gemm<<<512, 256, 0, stream>>>(x, Wbt, Qb, Kb, Vtb);
    attn_fwd<<<1024, 256, 0, stream>>>(Qb, Kb, Vtb, out);
}

// Round 8
// 254.880 us; speedup vs baseline: 1.5117x; 1.5117x over previous
//
#include <hip/hip_runtime.h>
#include <hip/hip_bf16.h>
#include <stdint.h>

// Problem: B=8, T=4096, C=1024, D=128 single-head causal attention, fp32 in/out.
// Pipeline: prep_w ; qkv_gemm (fused, x read once, reg-rotated prefetch) ;
// attn_fwd (flash attention, LDS-staged double-buffered K/V via global_load_lds,
// XOR-swizzled (pre-swizzled global src, m173 pattern), uniform work via in-block
// sequential pair (qt, 63-qt): 256 blocks x 65 KV-tiles each, no merge, no spill).

typedef __attribute__((ext_vector_type(8))) short short8;   // 8 bf16 (4 VGPRs)
typedef __attribute__((ext_vector_type(4))) float f32x4;
typedef __attribute__((ext_vector_type(4))) unsigned short u16x4;

#define NB 8
#define NT 4096
#define NC 1024
#define ND 128

__device__ __forceinline__ unsigned short f2bf(float f) {
    union { float f; uint32_t u; } v; v.f = f;
    uint32_t u = v.u;
    return (unsigned short)((u + 0x7FFFu + ((u >> 16) & 1u)) >> 16);  // RNE
}

// ---------------- W -> bf16, transposed: Wbt[w][n][k] = W_w[k][n] ----------------
__global__ void prep_w(const float* __restrict__ Wq, const float* __restrict__ Wk,
                       const float* __restrict__ Wv, unsigned short* __restrict__ Wbt) {
    int idx = blockIdx.x * 256 + threadIdx.x;          // 0 .. 3*128*1024-1
    int w = idx >> 17;                                  // 131072 per matrix
    int rem = idx & 131071;
    int n = rem >> 10;
    int k = rem & 1023;
    const float* W = (w == 0) ? Wq : (w == 1) ? Wk : Wv;
    Wbt[idx] = f2bf(W[k * ND + n]);
}

// ---------------- fused QKV projection: x[32768][1024] @ {Wq,Wk,Wv} ----------------
// grid 512: blockIdx.x = 64-row M-tile. x read once; next x-tile prefetched to regs
// while MFMA runs (hides HBM latency).
__global__ __launch_bounds__(256, 2)
void qkv_gemm(const float* __restrict__ x, const unsigned short* __restrict__ Wbt,
              unsigned short* __restrict__ Qo, unsigned short* __restrict__ Ko,
              unsigned short* __restrict__ Vto) {
    __shared__ __align__(16) unsigned short xl[64][40];   // 32 + 8 pad (bf16)
    const int mt = blockIdx.x;
    const int tid = threadIdx.x;
    const int lane = tid & 63;
    const int w = tid >> 6;
    const int wr = w >> 1, wc = w & 1;
    const int l15 = lane & 15, lg = lane >> 4;
    const int m0 = mt * 64;
    const int srow = tid >> 3, scol = (tid & 7) * 4;

    f32x4 acc[3][2][4];
#pragma unroll
    for (int nt = 0; nt < 3; ++nt)
#pragma unroll
        for (int mi = 0; mi < 2; ++mi)
#pragma unroll
            for (int ni = 0; ni < 4; ++ni) acc[nt][mi][ni] = (f32x4)0.0f;

    const float* xp0 = &x[(size_t)(m0 + srow) * NC + scol];
    const float* xp1 = &x[(size_t)(m0 + srow + 32) * NC + scol];

    f32x4 vc0 = *reinterpret_cast<const f32x4*>(xp0);
    f32x4 vc1 = *reinterpret_cast<const f32x4*>(xp1);

    for (int ks = 0; ks < 32; ++ks) {
        const int k0 = ks * 32;
        u16x4 b0, b1;
#pragma unroll
        for (int e = 0; e < 4; ++e) { b0[e] = f2bf(vc0[e]); b1[e] = f2bf(vc1[e]); }
        *reinterpret_cast<u16x4*>(&xl[srow][scol]) = b0;
        *reinterpret_cast<u16x4*>(&xl[srow + 32][scol]) = b1;
        __syncthreads();
        f32x4 vn0 = (f32x4)0.0f, vn1 = (f32x4)0.0f;
        if (ks < 31) {                      // prefetch next x tile under the MFMAs
            vn0 = *reinterpret_cast<const f32x4*>(xp0 + k0 + 32);
            vn1 = *reinterpret_cast<const f32x4*>(xp1 + k0 + 32);
        }
        short8 a0 = *reinterpret_cast<const short8*>(&xl[wr * 32 + l15][lg * 8]);
        short8 a1 = *reinterpret_cast<const short8*>(&xl[wr * 32 + 16 + l15][lg * 8]);
#pragma unroll
        for (int nt = 0; nt < 3; ++nt) {
            const unsigned short* Wn = Wbt + (size_t)nt * (ND * NC);
#pragma unroll
            for (int ni = 0; ni < 4; ++ni) {
                short8 bb = *reinterpret_cast<const short8*>(
                    &Wn[(size_t)(wc * 64 + ni * 16 + l15) * NC + k0 + lg * 8]);
                acc[nt][0][ni] = __builtin_amdgcn_mfma_f32_16x16x32_bf16(
                    a0, bb, acc[nt][0][ni], 0, 0, 0);
                acc[nt][1][ni] = __builtin_amdgcn_mfma_f32_16x16x32_bf16(
                    a1, bb, acc[nt][1][ni], 0, 0, 0);
            }
        }
        __syncthreads();
        vc0 = vn0; vc1 = vn1;
    }
    // epilogue: C/D layout col=lane&15, row=(lane>>4)*4+reg
#pragma unroll
    for (int nt = 0; nt < 3; ++nt)
#pragma unroll
        for (int mi = 0; mi < 2; ++mi)
#pragma unroll
            for (int ni = 0; ni < 4; ++ni)
#pragma unroll
                for (int r = 0; r < 4; ++r) {
                    int row = m0 + wr * 32 + mi * 16 + lg * 4 + r;
                    int col = wc * 64 + ni * 16 + l15;
                    unsigned short bv = f2bf(acc[nt][mi][ni][r]);
                    if (nt == 0) Qo[(size_t)row * ND + col] = bv;
                    else if (nt == 1) Ko[(size_t)row * ND + col] = bv;
                    else {
                        int bb2 = row >> 12, t = row & 4095;
                        Vto[((size_t)(bb2 * ND + col)) * NT + t] = bv;
                    }
                }
}

// ---------------- flash attention, causal, LDS-staged double-buffered K/V ----------------
// 256 blocks x 256 threads; block -> (batch b = bid&7, pair p = bid>>3 in [0,32)).
// Sequential halves qt = p then qt = 63-p -> every block runs exactly 65 KV tiles
// (uniform work, no dispatcher assumptions). 4 waves each own 16 q rows end-to-end
// (no cross-wave merge -> low VGPR, no spill). K/V tiles (16KB each) staged via
// global_load_lds (16B, async) into double-buffered LDS; XOR swizzle byte^=((row&7)<<4)
// applied on the GLOBAL source (LDS dest must stay linear) and on the ds_read side.
__global__ __launch_bounds__(256, 2)
void attn_fwd(const unsigned short* __restrict__ Q, const unsigned short* __restrict__ K,
              const unsigned short* __restrict__ Vt, float* __restrict__ out) {
    __shared__ __align__(16) unsigned short Kl[2][64 * 128];   // [kv 64][d 128] bf16, swizzled
    __shared__ __align__(16) unsigned short Vl[2][128 * 64];   // [d 128][s 64] bf16, swizzled
    __shared__ __align__(16) unsigned short plds[4][16][72];   // per-wave P buffer

    const int bid = blockIdx.x;
    const int p = bid >> 3, b = bid & 7;
    const int tid = threadIdx.x;
    const int w = tid >> 6, lane = tid & 63;
    const int l15 = lane & 15, lg = lane >> 4;

    const float sc = 0.08838834764831845f;     // 1/sqrt(128)
    const float L2E = 1.4426950408889634f;

    const unsigned short* Kbase = &K[(size_t)b * NT * ND];
    const unsigned short* Vbase = &Vt[(size_t)b * ND * NT];

    // stage one 64-wide KV tile (K: 64x256B, V: 128x128B) into buffer `buf`
    auto stage = [&](int buf, int s0) {
#pragma unroll
        for (int r = 0; r < 4; ++r) {          // K tile: 4 rounds x 4KB
            int off = r * 4096 + w * 1024 + lane * 16;
            int row = off >> 8;
            int gcol = (off & 255) ^ ((row & 7) << 4);
            const unsigned short* src = Kbase + (size_t)(s0 + row) * ND + (gcol >> 1);
            __builtin_amdgcn_global_load_lds(
                (const __attribute__((address_space(1))) void*)src,
                (__attribute__((address_space(3))) void*)&Kl[buf][(r * 4096 + w * 1024) >> 1],
                16, 0, 0);
        }
#pragma unroll
        for (int r = 0; r < 4; ++r) {          // V tile: 4 rounds x 4KB
            int off = r * 4096 + w * 1024 + lane * 16;
            int row = off >> 7;
            int gcol = (off & 127) ^ ((row & 7) << 4);
            const unsigned short* src = Vbase + (size_t)row * NT + s0 + (gcol >> 1);
            __builtin_amdgcn_global_load_lds(
                (const __attribute__((address_space(1))) void*)src,
                (__attribute__((address_space(3))) void*)&Vl[buf][(r * 4096 + w * 1024) >> 1],
                16, 0, 0);
        }
    };

    for (int half = 0; half < 2; ++half) {
        const int qt = half ? (63 - p) : p;
        const int qb0 = qt * 64;
        const int qw0 = qb0 + w * 16;
        const int ntiles = qt + 1;

        // Q fragments (hoisted): A-frag lane l holds Q[m=l&15][k-chunk per l>>4]
        short8 qf[4];
        const size_t qbase = ((size_t)b * NT + qw0 + l15) * ND;
#pragma unroll
        for (int c = 0; c < 4; ++c)
            qf[c] = *reinterpret_cast<const short8*>(&Q[qbase + c * 32 + lg * 8]);

        f32x4 o[8];
#pragma unroll
        for (int jn = 0; jn < 8; ++jn) o[jn] = (f32x4)0.0f;
        float mrow[4], lsum[4];
#pragma unroll
        for (int r = 0; r < 4; ++r) { mrow[r] = -1e30f; lsum[r] = 0.0f; }

        stage(0, 0);
        __syncthreads();                       // drains vmcnt: tile 0 ready
        int cur = 0;

        for (int t = 0; t < ntiles; ++t) {
            const int s0 = t * 64;
            if (t + 1 < ntiles) stage(cur ^ 1, s0 + 64);   // async prefetch next tile

            // ---- S = Q K^T from Kl[cur] ----
            const unsigned short* KlC = &Kl[cur][0];
            f32x4 s[4];
#pragma unroll
            for (int j = 0; j < 4; ++j) s[j] = (f32x4)0.0f;
            __builtin_amdgcn_s_setprio(1);
#pragma unroll
            for (int j = 0; j < 4; ++j) {
                const int row = j * 16 + l15;
                const int cb = (row & 7) << 4;
#pragma unroll
                for (int c = 0; c < 4; ++c) {
                    short8 kf = *reinterpret_cast<const short8*>(
                        &KlC[row * 128 + (((c * 64 + lg * 16) ^ cb) >> 1)]);
                    s[j] = __builtin_amdgcn_mfma_f32_16x16x32_bf16(qf[c], kf, s[j], 0, 0, 0);
                }
            }
            __builtin_amdgcn_s_setprio(0);

            // ---- prefetch V half (jn=0..3) from LDS: hides under softmax ----
            const unsigned short* VlC = &Vl[cur][0];
            short8 vf0[8];
#pragma unroll
            for (int jn = 0; jn < 4; ++jn) {
                const int row = jn * 16 + l15;
                const int cb = (row & 7) << 4;
#pragma unroll
                for (int kc = 0; kc < 2; ++kc)
                    vf0[jn * 2 + kc] = *reinterpret_cast<const short8*>(
                        &VlC[row * 64 + (((kc * 64 + lg * 16) ^ cb) >> 1)]);
            }

            // ---- softmax (online) ----
            const bool diag = (s0 + 64 > qw0);
            float tmax[4];
#pragma unroll
            for (int r = 0; r < 4; ++r) tmax[r] = -1e30f;
#pragma unroll
            for (int j = 0; j < 4; ++j)
#pragma unroll
                for (int r = 0; r < 4; ++r) {
                    float sv = s[j][r] * sc;
                    if (diag) {
                        int qrow = qw0 + lg * 4 + r;
                        int scol = s0 + j * 16 + l15;
                        if (scol > qrow) sv = -1e30f;
                    }
                    s[j][r] = sv;
                    tmax[r] = fmaxf(tmax[r], sv);
                }
#pragma unroll
            for (int r = 0; r < 4; ++r) {
#pragma unroll
                for (int off = 1; off < 16; off <<= 1)
                    tmax[r] = fmaxf(tmax[r], __shfl_xor(tmax[r], off, 64));
            }
            float alpha[4], psum[4];
#pragma unroll
            for (int r = 0; r < 4; ++r) {
                float mn = fmaxf(mrow[r], tmax[r]);
                alpha[r] = exp2f((mrow[r] - mn) * L2E);
                mrow[r] = mn;
                psum[r] = 0.0f;
            }
#pragma unroll
            for (int j = 0; j < 4; ++j)
#pragma unroll
                for (int r = 0; r < 4; ++r) {
                    float pv = exp2f((s[j][r] - mrow[r]) * L2E);
                    s[j][r] = pv;
                    psum[r] += pv;
                }
#pragma unroll
            for (int r = 0; r < 4; ++r) {
#pragma unroll
                for (int off = 1; off < 16; off <<= 1)
                    psum[r] += __shfl_xor(psum[r], off, 64);
                lsum[r] = lsum[r] * alpha[r] + psum[r];
            }
            // rescale O
#pragma unroll
            for (int jn = 0; jn < 8; ++jn)
#pragma unroll
                for (int r = 0; r < 4; ++r) o[jn][r] *= alpha[r];

            // ---- P -> LDS (D-layout coords), reload as A-frags ----
#pragma unroll
            for (int j = 0; j < 4; ++j)
#pragma unroll
                for (int r = 0; r < 4; ++r)
                    plds[w][lg * 4 + r][j * 16 + l15] = f2bf(s[j][r]);
            asm volatile("s_waitcnt lgkmcnt(0)" ::: "memory");
            short8 pa[2];
#pragma unroll
            for (int kc = 0; kc < 2; ++kc)
                pa[kc] = *reinterpret_cast<const short8*>(&plds[w][l15][kc * 32 + lg * 8]);

            // ---- O += P V : half 0 from prefetched regs, half 1 from LDS ----
            __builtin_amdgcn_s_setprio(1);
#pragma unroll
            for (int jn = 0; jn < 4; ++jn)
#pragma unroll
                for (int kc = 0; kc < 2; ++kc)
                    o[jn] = __builtin_amdgcn_mfma_f32_16x16x32_bf16(
                        pa[kc], vf0[jn * 2 + kc], o[jn], 0, 0, 0);
#pragma unroll
            for (int jn = 4; jn < 8; ++jn) {
                const int row = jn * 16 + l15;
                const int cb = (row & 7) << 4;
#pragma unroll
                for (int kc = 0; kc < 2; ++kc) {
                    short8 vf = *reinterpret_cast<const short8*>(
                        &VlC[row * 64 + (((kc * 64 + lg * 16) ^ cb) >> 1)]);
                    o[jn] = __builtin_amdgcn_mfma_f32_16x16x32_bf16(pa[kc], vf, o[jn], 0, 0, 0);
                }
            }
            __builtin_amdgcn_s_setprio(0);

            __syncthreads();                   // prefetch done (vmcnt) + reads drained
            cur ^= 1;
        }

        // ---- epilogue: each wave writes its own 16 rows ----
        float il[4];
#pragma unroll
        for (int r = 0; r < 4; ++r) il[r] = 1.0f / lsum[r];
#pragma unroll
        for (int jn = 0; jn < 8; ++jn)
#pragma unroll
            for (int r = 0; r < 4; ++r)
                out[((size_t)b * NT + qw0 + lg * 4 + r) * ND + jn * 16 + l15] =
                    o[jn][r] * il[r];
    }
}

extern "C" void kernel_launch(void* const* d_in, const int* in_sizes, int n_in,
                              void* d_out, int out_size, void* d_ws, size_t ws_size,
                              hipStream_t stream) {
    const float* x  = (const float*)d_in[0];
    const float* Wq = (const float*)d_in[1];
    const float* Wk = (const float*)d_in[2];
    const float* Wv = (const float*)d_in[3];
    float* out = (float*)d_out;

    unsigned short* ws  = (unsigned short*)d_ws;
    unsigned short* Wbt = ws;                               // 3*128*1024
    unsigned short* Qb  = Wbt + 3 * ND * NC;                // 8*4096*128
    unsigned short* Kb  = Qb + (size_t)NB * NT * ND;
    unsigned short* Vtb = Kb + (size_t)NB * NT * ND;        // transposed [B][D][T]

    prep_w<<<1536, 256, 0, stream>>>(Wq, Wk, Wv, Wbt);
    qkv_gemm<<<512, 256, 0, stream>>>(x, Wbt, Qb, Kb, Vtb);
    attn_fwd<<<256, 256, 0, stream>>>(Qb, Kb, Vtb, out);
}